// Round 7
// baseline (990.458 us; speedup 1.0000x reference)
//
#include <hip/hip_runtime.h>
#include <hip/hip_bf16.h>

typedef __attribute__((ext_vector_type(8))) short short8;
typedef __attribute__((ext_vector_type(4))) float floatx4;
typedef unsigned short u16;

#define GLDS16(gp, lp) __builtin_amdgcn_global_load_lds(                        \
    (const __attribute__((address_space(1))) void*)(gp),                        \
    (__attribute__((address_space(3))) void*)(lp), 16, 0, 0)

__device__ inline u16 f2bf(float f) {
    unsigned u = __float_as_uint(f);
    unsigned r = (u + 0x7fffu + ((u >> 16) & 1u)) >> 16;
    return (u16)r;
}

// ---------------- block reduce (sum, sumsq) over 256 threads ----------------
__device__ inline void block_reduce2(float& s, float& ss) {
    #pragma unroll
    for (int o = 32; o > 0; o >>= 1) {
        s  += __shfl_down(s, o);
        ss += __shfl_down(ss, o);
    }
    __shared__ float red[8];
    const int t = threadIdx.x;
    if ((t & 63) == 0) { red[t >> 6] = s; red[4 + (t >> 6)] = ss; }
    __syncthreads();
    s  = red[0] + red[1] + red[2] + red[3];
    ss = red[4] + red[5] + red[6] + red[7];
}

// =============== NEW: 256x256 bf16 MFMA GEMM, 8 waves, BK=32, ring-4 ===============
// One barrier + one counted vmcnt per K-step; staging (4 GLDS split across the two
// compute phases) targets buf[(t+3)&3], which the top-of-step barrier proves free.
// Full-spread LDS swizzle: bank-quad = (4*row + slot) mod 8 -> slot_lds =
// slot_data ^ ((row>>1)&3); applied on GLDS *source* + ds_read (involution).
// C[M][N] = A(MxK)*B^T, A row-major [M][K], B [N][K]. EPI=2: relu(x+P1[n]).
// CMODE: 4 = bf16 row-major store; 2 = colsum atomicAdd into out[m0>>12][n].
template<int EPI, int CMODE>
__global__ __launch_bounds__(512, 2)
void gemm256(const u16* __restrict__ A, const u16* __restrict__ B,
             const float* __restrict__ P1, void* __restrict__ Cv,
             int Kc, int lda, int ldb, int ldc)
{
    __shared__ short L[4][16384];   // ring-4: per buf A[256][32] (8192h) + B[256][32] (8192h)
    __shared__ float red2[2][256];

    const int t = threadIdx.x;
    const int w = t >> 6, l = t & 63;
    const int wr = w >> 2, wc = w & 3;          // wave -> (2m x 4n), 128x64 out per wave
    const int l16 = l & 15, lr = l >> 4;

    // T1 XCD swizzle (nwg % 8 == 0)
    const int nwg = gridDim.x * gridDim.y;
    const int bid = blockIdx.y * gridDim.x + blockIdx.x;
    const int cpx = nwg >> 3;
    const int sw  = (bid & 7) * cpx + (bid >> 3);
    const int n0 = (sw % gridDim.x) * 256;
    const int m0 = (sw / gridDim.x) * 256;

    // staging: GLDS g covers rows g*128 + w*16 + l/4, LDS slot l&3 (linear dest);
    // source fetches data slot (l&3) ^ ((row>>1)&3)  [swizzle involution]
    const int r0 = w * 16 + (l >> 2);
    const int sl = l & 3;
    const u16* aS[2]; const u16* bS[2];
    #pragma unroll
    for (int g = 0; g < 2; ++g) {
        const int r  = g * 128 + r0;
        const int ks = (sl ^ ((r >> 1) & 3)) * 8;
        aS[g] = A + (size_t)(m0 + r) * lda + ks;
        bS[g] = B + (size_t)(n0 + r) * ldb + ks;
    }

    auto stageA = [&](int tt) {
        short* d = L[tt & 3];
        GLDS16(aS[0] + tt * 32, d + w * 512);
        GLDS16(aS[1] + tt * 32, d + 4096 + w * 512);
    };
    auto stageB = [&](int tt) {
        short* d = L[tt & 3] + 8192;
        GLDS16(bS[0] + tt * 32, d + w * 512);
        GLDS16(bS[1] + tt * 32, d + 4096 + w * 512);
    };

    // fragment read offsets (halfwords), swizzled
    int aOff[8], bOff[4];
    #pragma unroll
    for (int m = 0; m < 8; ++m) {
        const int row = wr * 128 + m * 16 + l16;
        aOff[m] = row * 32 + ((lr ^ ((row >> 1) & 3)) * 8);
    }
    #pragma unroll
    for (int n = 0; n < 4; ++n) {
        const int row = wc * 64 + n * 16 + l16;
        bOff[n] = 8192 + row * 32 + ((lr ^ ((row >> 1) & 3)) * 8);
    }

    floatx4 acc[8][4] = {};
    const int nsteps = Kc >> 5;

    // prologue: 3 tiles in flight (12 GLDS per wave)
    stageA(0); stageB(0); stageA(1); stageB(1); stageA(2); stageB(2);

    for (int tt = 0; tt < nsteps; ++tt) {
        if (tt <= nsteps - 3)      asm volatile("s_waitcnt vmcnt(8)" ::: "memory");
        else if (tt == nsteps - 2) asm volatile("s_waitcnt vmcnt(4)" ::: "memory");
        else                       asm volatile("s_waitcnt vmcnt(0)" ::: "memory");
        __builtin_amdgcn_s_barrier();          // tile tt complete; buf[(tt+3)&3] free
        __builtin_amdgcn_sched_barrier(0);

        const short* buf = L[tt & 3];
        const bool pre = (tt + 3 < nsteps);
        short8 af[4], bfr[4];

        // ---- phase A: stage A(t+3) | read B-frags + A-frags m0-3 | 16 MFMA ----
        if (pre) stageA(tt + 3);
        #pragma unroll
        for (int n = 0; n < 4; ++n)
            bfr[n] = *reinterpret_cast<const short8*>(&buf[bOff[n]]);
        #pragma unroll
        for (int m = 0; m < 4; ++m)
            af[m] = *reinterpret_cast<const short8*>(&buf[aOff[m]]);
        __builtin_amdgcn_s_setprio(1);
        #pragma unroll
        for (int m = 0; m < 4; ++m)
            #pragma unroll
            for (int n = 0; n < 4; ++n)
                acc[m][n] = __builtin_amdgcn_mfma_f32_16x16x32_bf16(af[m], bfr[n], acc[m][n], 0, 0, 0);
        __builtin_amdgcn_s_setprio(0);

        // ---- phase B: stage B(t+3) | read A-frags m4-7 | 16 MFMA ----
        if (pre) stageB(tt + 3);
        #pragma unroll
        for (int m = 0; m < 4; ++m)
            af[m] = *reinterpret_cast<const short8*>(&buf[aOff[4 + m]]);
        __builtin_amdgcn_s_setprio(1);
        #pragma unroll
        for (int m = 0; m < 4; ++m)
            #pragma unroll
            for (int n = 0; n < 4; ++n)
                acc[4 + m][n] = __builtin_amdgcn_mfma_f32_16x16x32_bf16(af[m], bfr[n], acc[4 + m][n], 0, 0, 0);
        __builtin_amdgcn_s_setprio(0);
        // no trailing barrier: next iteration's top barrier covers LDS reuse
    }

    if (CMODE == 2) {   // fused colsum of relu(acc + P1) -> atomicAdd per image row
        float csum[4];
        #pragma unroll
        for (int n = 0; n < 4; ++n) {
            const int col = n0 + wc * 64 + n * 16 + l16;
            const float b1 = P1[col];
            float s = 0.f;
            #pragma unroll
            for (int m = 0; m < 8; ++m)
                #pragma unroll
                for (int r = 0; r < 4; ++r)
                    s += fmaxf(acc[m][n][r] + b1, 0.f);
            s += __shfl_xor(s, 16);
            s += __shfl_xor(s, 32);
            csum[n] = s;
        }
        if (l < 16) {
            #pragma unroll
            for (int n = 0; n < 4; ++n)
                red2[wr][wc * 64 + n * 16 + l16] = csum[n];
        }
        __syncthreads();
        if (t < 256) {
            float* C = (float*)Cv + (size_t)(m0 >> 12) * ldc;
            atomicAdd(&C[n0 + t], red2[0][t] + red2[1][t]);
        }
        return;
    }

    // CMODE 4: bf16 store with relu+bias
    u16* C = (u16*)Cv;
    #pragma unroll
    for (int m = 0; m < 8; ++m) {
        #pragma unroll
        for (int n = 0; n < 4; ++n) {
            const int col = n0 + wc * 64 + n * 16 + l16;
            const float b1 = P1[col];
            #pragma unroll
            for (int r = 0; r < 4; ++r) {
                const int row = m0 + wr * 128 + m * 16 + lr * 4 + r;
                C[(size_t)row * ldc + col] = f2bf(fmaxf(acc[m][n][r] + b1, 0.f));
            }
        }
    }
}

// =============== bf16 MFMA GEMM, 128x128 tile, 4 waves, BK=32, ring-3 (unchanged) ======
template<int AMODE, int EPI, int CMODE>
__global__ __launch_bounds__(256)
void gemm_bf16(const u16* __restrict__ A, const u16* __restrict__ B,
               const float* __restrict__ P1, const float* __restrict__ P2,
               void* __restrict__ Cv,
               int M, int N, int Kc, int lda, int ldb, int ldc)
{
    __shared__ short As[3][4096];
    __shared__ short Bs[3][4096];

    const int t  = threadIdx.x;
    const int w  = t >> 6, l = t & 63;
    const int wr = w >> 1, wc = w & 1;
    const int l16 = l & 15, lr = l >> 4;

    const int nwg = gridDim.x * gridDim.y;
    const int bid = blockIdx.y * gridDim.x + blockIdx.x;
    const int cpx = nwg >> 3;
    const int sw  = (bid & 7) * cpx + (bid >> 3);
    const int n0 = (sw % gridDim.x) * 128;
    const int m0 = (sw / gridDim.x) * 128;
    const int kbase = blockIdx.z * Kc;

    const int srow  = w * 16 + (l >> 2);
    const int skoff = (((l & 3) ^ ((l >> 2) & 3)) * 8);

    const u16* aRow0 = nullptr; const u16* aRow1 = nullptr;
    size_t aSp0 = 0, aSp1 = 0;
    if (AMODE == 0) {
        aRow0 = A + (size_t)(m0 + srow) * lda + kbase + skoff;
        aRow1 = A + (size_t)(m0 + 64 + srow) * lda + kbase + skoff;
    } else {
        const int r0 = m0 + srow, r1 = r0 + 64;
        const int roi0 = r0 / 49, sp0 = r0 - roi0 * 49;
        const int roi1 = r1 / 49, sp1 = r1 - roi1 * 49;
        aSp0 = ((size_t)roi0 * 81 + (sp0 / 7) * 9 + (sp0 % 7)) * 1024 + skoff;
        aSp1 = ((size_t)roi1 * 81 + (sp1 / 7) * 9 + (sp1 % 7)) * 1024 + skoff;
    }
    const u16* bRow0 = B + (size_t)(n0 + srow) * ldb + kbase + skoff;
    const u16* bRow1 = B + (size_t)(n0 + 64 + srow) * ldb + kbase + skoff;

    auto stage = [&](int buf, int k0) {
        if (AMODE == 0) {
            GLDS16(aRow0 + k0, As[buf] + w * 512);
            GLDS16(aRow1 + k0, As[buf] + 2048 + w * 512);
        } else {
            const int kk  = kbase + k0;
            const int tap = kk >> 10;
            const size_t off = (size_t)((tap / 3) * 9 + (tap % 3)) * 1024 + (kk & 1023);
            GLDS16(A + aSp0 + off, As[buf] + w * 512);
            GLDS16(A + aSp1 + off, As[buf] + 2048 + w * 512);
        }
        GLDS16(bRow0 + k0, Bs[buf] + w * 512);
        GLDS16(bRow1 + k0, Bs[buf] + 2048 + w * 512);
    };

    floatx4 acc[4][4] = {};

    auto compute = [&](int buf) {
        const short* as = As[buf];
        const short* bs = Bs[buf];
        short8 af[4], bfr[4];
        #pragma unroll
        for (int i = 0; i < 4; ++i) {
            const int row = wr * 64 + i * 16 + l16;
            af[i] = *reinterpret_cast<const short8*>(&as[row * 32 + ((lr ^ (row & 3)) * 8)]);
        }
        #pragma unroll
        for (int j = 0; j < 4; ++j) {
            const int row = wc * 64 + j * 16 + l16;
            bfr[j] = *reinterpret_cast<const short8*>(&bs[row * 32 + ((lr ^ (row & 3)) * 8)]);
        }
        __builtin_amdgcn_s_setprio(1);
        #pragma unroll
        for (int i = 0; i < 4; ++i)
            #pragma unroll
            for (int j = 0; j < 4; ++j)
                acc[i][j] = __builtin_amdgcn_mfma_f32_16x16x32_bf16(af[i], bfr[j], acc[i][j], 0, 0, 0);
        __builtin_amdgcn_s_setprio(0);
    };

    const int nsteps = Kc >> 5;

    stage(0, 0); stage(1, 32); stage(2, 64);

    for (int i = 0; i < nsteps - 2; ++i) {
        asm volatile("s_waitcnt vmcnt(8)" ::: "memory");
        __builtin_amdgcn_s_barrier();
        __builtin_amdgcn_sched_barrier(0);
        compute(i % 3);
        __builtin_amdgcn_sched_barrier(0);
        __builtin_amdgcn_s_barrier();
        __builtin_amdgcn_sched_barrier(0);
        if (i < nsteps - 3) stage(i % 3, (i + 3) * 32);
    }
    {
        const int i = nsteps - 2;
        asm volatile("s_waitcnt vmcnt(4)" ::: "memory");
        __builtin_amdgcn_s_barrier();
        __builtin_amdgcn_sched_barrier(0);
        compute(i % 3);
    }
    {
        const int i = nsteps - 1;
        asm volatile("s_waitcnt vmcnt(0)" ::: "memory");
        __builtin_amdgcn_s_barrier();
        __builtin_amdgcn_sched_barrier(0);
        compute(i % 3);
    }

    const int mBase = m0 + wr * 64;
    const int nBase = n0 + wc * 64;

    if (CMODE == 2) {
        __shared__ float red2[2][128];
        float csum[4];
        #pragma unroll
        for (int j = 0; j < 4; ++j) {
            const int n = nBase + j * 16 + l16;
            const float b1 = P1[n];
            float s = 0.f;
            #pragma unroll
            for (int i = 0; i < 4; ++i)
                #pragma unroll
                for (int r = 0; r < 4; ++r)
                    s += fmaxf(acc[i][j][r] + b1, 0.f);
            s += __shfl_xor(s, 16);
            s += __shfl_xor(s, 32);
            csum[j] = s;
        }
        __syncthreads();
        if (l < 16) {
            #pragma unroll
            for (int j = 0; j < 4; ++j)
                red2[wr][wc * 64 + j * 16 + l16] = csum[j];
        }
        __syncthreads();
        float* C = (float*)Cv + (size_t)(m0 >> 12) * ldc;
        if (t < 128) atomicAdd(&C[n0 + t], red2[0][t] + red2[1][t]);
        return;
    }

    #pragma unroll
    for (int i = 0; i < 4; ++i) {
        #pragma unroll
        for (int j = 0; j < 4; ++j) {
            const int n = nBase + j * 16 + l16;
            const float b1 = (EPI >= 1) ? P1[n] : 0.f;
            const float b2 = (EPI == 3) ? P2[n] : 0.f;
            #pragma unroll
            for (int r = 0; r < 4; ++r) {
                float v = acc[i][j][r];
                if (EPI == 1)      v += b1;
                else if (EPI == 2) v = fmaxf(v + b1, 0.f);
                else if (EPI == 3) v = fmaxf(v * b1 + b2, 0.f);
                const int m = mBase + i * 16 + lr * 4 + r;
                if (CMODE == 0)      ((float*)Cv)[(size_t)m * ldc + n] = v;
                else if (CMODE == 4) ((u16*)Cv)[(size_t)m * ldc + n] = f2bf(v);
                else if (CMODE == 3) atomicAdd(&((float*)Cv)[(size_t)m * ldc + n], v);
                else if (CMODE == 1) {
                    const int roi = m / 49, sp = m - roi * 49;
                    ((u16*)Cv)[(size_t)roi * 12544 + n * 49 + sp] = f2bf(v);
                }
            }
        }
    }
}

// ---------------- im_feat [8][2048][256] f32 -> [8][256][2048] bf16 (LDS transpose) -------
__global__ __launch_bounds__(256)
void transpose_proj(const float* __restrict__ in, u16* __restrict__ out)
{
    __shared__ float tile[64][65];
    const int b = blockIdx.z;
    const int c0 = blockIdx.y * 64;
    const int h0 = blockIdx.x * 64;
    const int t = threadIdx.x;
    const float* src = in + ((size_t)b * 2048 + c0) * 256 + h0;
    #pragma unroll
    for (int p = 0; p < 16; ++p) {
        const int idx = p * 256 + t;
        const int r = idx >> 6, c = idx & 63;
        tile[r][c] = src[(size_t)r * 256 + c];
    }
    __syncthreads();
    u16* dst = out + ((size_t)b * 256 + h0) * 2048 + c0;
    #pragma unroll
    for (int p = 0; p < 16; ++p) {
        const int idx = p * 256 + t;
        const int r = idx >> 6, c = idx & 63;
        dst[(size_t)r * 2048 + c] = f2bf(tile[c][r]);
    }
}

// ---------------- zero the 1-pixel halo of r_pad [512][81][1024] bf16 ----------------
__global__ __launch_bounds__(256)
void zero_halo(u16* __restrict__ r_pad)
{
    const int blk = blockIdx.x;
    const int roi = blk >> 5, h = blk & 31;
    int p;
    if (h < 9)       p = h;
    else if (h < 18) p = 72 + (h - 9);
    else { const int r = (h - 18) >> 1, s = (h - 18) & 1; p = (r + 1) * 9 + s * 8; }
    uint2* o = reinterpret_cast<uint2*>(r_pad + ((size_t)roi * 81 + p) * 1024);
    o[threadIdx.x] = make_uint2(0u, 0u);
}

// ---------------- ROIAlignV2 (aligned=true), 2x2 samples/bin -> r_pad interior bf16 -------
__global__ __launch_bounds__(256)
void roialign_kernel(const float* __restrict__ x_cl, const float* __restrict__ boxes,
                     u16* __restrict__ r_pad)
{
    const int blk = blockIdx.x;
    const int n = blk / 49, bin = blk % 49;
    const int py = bin / 7, px = bin % 7;
    const int b = n >> 6;
    const float* roi = boxes + n * 4;
    const float x1 = roi[0] * (1.f/32.f) - 0.5f;
    const float y1 = roi[1] * (1.f/32.f) - 0.5f;
    const float bw = (roi[2] - roi[0]) * (1.f/32.f) * (1.0f / 7.0f);
    const float bh = (roi[3] - roi[1]) * (1.f/32.f) * (1.0f / 7.0f);
    const int t = threadIdx.x;

    float acc[4] = {0.f, 0.f, 0.f, 0.f};
    #pragma unroll
    for (int sy = 0; sy < 2; ++sy) {
        #pragma unroll
        for (int sx = 0; sx < 2; ++sx) {
            const float yv = y1 + bh * ((float)(py * 2 + sy) + 0.5f) * 0.5f;
            const float xv = x1 + bw * ((float)(px * 2 + sx) + 0.5f) * 0.5f;
            const bool vy = (yv >= -1.0f) && (yv <= 16.0f);
            const bool vx = (xv >= -1.0f) && (xv <= 16.0f);
            if (!(vy && vx)) continue;
            float yc = fmaxf(yv, 0.f);
            int yl = (int)floorf(yc);
            int yh; if (yl >= 15) { yl = 15; yc = 15.f; yh = 15; } else yh = yl + 1;
            const float wy = yc - (float)yl;
            float xc = fmaxf(xv, 0.f);
            int xl = (int)floorf(xc);
            int xh; if (xl >= 15) { xl = 15; xc = 15.f; xh = 15; } else xh = xl + 1;
            const float wx = xc - (float)xl;

            const float w00 = (1.f - wy) * (1.f - wx), w01 = (1.f - wy) * wx;
            const float w10 = wy * (1.f - wx),         w11 = wy * wx;
            const float* p00 = x_cl + ((size_t)b * 256 + yl * 16 + xl) * 1024;
            const float* p01 = x_cl + ((size_t)b * 256 + yl * 16 + xh) * 1024;
            const float* p10 = x_cl + ((size_t)b * 256 + yh * 16 + xl) * 1024;
            const float* p11 = x_cl + ((size_t)b * 256 + yh * 16 + xh) * 1024;
            #pragma unroll
            for (int cc = 0; cc < 4; ++cc) {
                const int c = t + cc * 256;
                acc[cc] += w00 * p00[c] + w01 * p01[c] + w10 * p10[c] + w11 * p11[c];
            }
        }
    }
    u16* o = r_pad + ((size_t)n * 81 + (py + 1) * 9 + (px + 1)) * 1024;
    #pragma unroll
    for (int cc = 0; cc < 4; ++cc) o[t + cc * 256] = f2bf(acc[cc] * 0.25f);
}

// ---------------- conv weight pack (tap-major K) bf16 + BN fold ----------------
__global__ __launch_bounds__(256)
void pack_conv(const float* __restrict__ conv_w, const float* __restrict__ conv_b,
               const float* __restrict__ bn_g, const float* __restrict__ bn_b,
               const float* __restrict__ bn_m, const float* __restrict__ bn_v,
               u16* __restrict__ wpack, float* __restrict__ scale, float* __restrict__ shift)
{
    const long idx = (long)blockIdx.x * 256 + threadIdx.x;
    if (idx < 2359296L) {
        const int oc = (int)(idx / 9216), k = (int)(idx % 9216);
        const int tap = k >> 10, ic = k & 1023;
        wpack[idx] = f2bf(conv_w[(long)oc * 9216 + ic * 9 + tap]);
    }
    if (idx < 256) {
        const float s = bn_g[idx] * rsqrtf(bn_v[idx] + 1e-5f);
        scale[idx] = s;
        shift[idx] = (conv_b[idx] - bn_m[idx]) * s + bn_b[idx];
    }
}

// ---------------- straight f32 -> bf16 convert (xN/4) ----------------
__global__ __launch_bounds__(256)
void cvt_bf16(const float* __restrict__ in, u16* __restrict__ out, int n4)
{
    const int i = blockIdx.x * 256 + threadIdx.x;
    if (i < n4) {
        const float4 v = reinterpret_cast<const float4*>(in)[i];
        ushort4 o; o.x = f2bf(v.x); o.y = f2bf(v.y); o.z = f2bf(v.z); o.w = f2bf(v.w);
        reinterpret_cast<ushort4*>(out)[i] = o;
    }
}

// ---------------- g1_w [1280][2560] f32 -> [2560][1280] bf16 (U rows then V rows) ----------
__global__ __launch_bounds__(256)
void pack_g1(const float* __restrict__ g1w, u16* __restrict__ out)
{
    const int j = blockIdx.x * 256 + threadIdx.x;
    if (j >= 2560 * 320) return;
    const int np = j / 320, k4 = (j - np * 320) * 4;
    const int srow = (np < 1280) ? np : np - 1280;
    const int soff = (np < 1280) ? 0 : 1280;
    const float4 v = *reinterpret_cast<const float4*>(&g1w[(size_t)srow * 2560 + soff + k4]);
    ushort4 o; o.x = f2bf(v.x); o.y = f2bf(v.y); o.z = f2bf(v.z); o.w = f2bf(v.w);
    *reinterpret_cast<ushort4*>(&out[(size_t)np * 1280 + k4]) = o;
}

// ---------------- fc bias + relu + LayerNorm(1024) -> feats[:, :1024] bf16 ----------------
__global__ __launch_bounds__(256)
void ln1_kernel(const float* __restrict__ in, const float* __restrict__ fb,
                const float* __restrict__ g, const float* __restrict__ b,
                u16* __restrict__ feats)
{
    const int n = blockIdx.x, t = threadIdx.x;
    float4 v = *reinterpret_cast<const float4*>(in + (size_t)n * 1024 + t * 4);
    const float4 bb = *reinterpret_cast<const float4*>(fb + t * 4);
    v.x = fmaxf(v.x + bb.x, 0.f); v.y = fmaxf(v.y + bb.y, 0.f);
    v.z = fmaxf(v.z + bb.z, 0.f); v.w = fmaxf(v.w + bb.w, 0.f);
    float s  = v.x + v.y + v.z + v.w;
    float ss = v.x*v.x + v.y*v.y + v.z*v.z + v.w*v.w;
    block_reduce2(s, ss);
    const float mu  = s * (1.f / 1024.f);
    const float var = ss * (1.f / 1024.f) - mu * mu;
    const float r   = rsqrtf(var + 1e-5f);
    const float4 gp = *reinterpret_cast<const float4*>(g + t * 4);
    const float4 bp = *reinterpret_cast<const float4*>(b + t * 4);
    ushort4 o;
    o.x = f2bf((v.x - mu) * r * gp.x + bp.x);
    o.y = f2bf((v.y - mu) * r * gp.y + bp.y);
    o.z = f2bf((v.z - mu) * r * gp.z + bp.z);
    o.w = f2bf((v.w - mu) * r * gp.w + bp.w);
    *reinterpret_cast<ushort4*>(feats + (size_t)n * 1280 + t * 4) = o;
}

// ---------------- box branch -> feats[:, 1024:1280] bf16 ----------------
__global__ __launch_bounds__(256)
void box_kernel(const float* __restrict__ nb, const float* __restrict__ bw,
                const float* __restrict__ bb, const float* __restrict__ g,
                const float* __restrict__ be, u16* __restrict__ feats)
{
    const int n = blockIdx.x, j = threadIdx.x;
    const float4 q = *reinterpret_cast<const float4*>(nb + n * 4);
    const float4 w = *reinterpret_cast<const float4*>(bw + j * 4);
    const float v = (q.x * 2.f - 1.f) * w.x + (q.y * 2.f - 1.f) * w.y
                  + (q.z * 2.f - 1.f) * w.z + (q.w * 2.f - 1.f) * w.w + bb[j];
    float s = v, ss = v * v;
    block_reduce2(s, ss);
    const float mu  = s * (1.f / 256.f);
    const float var = ss * (1.f / 256.f) - mu * mu;
    feats[(size_t)n * 1280 + 1024 + j] = f2bf((v - mu) * rsqrtf(var + 1e-5f) * g[j] + be[j]);
}

// ---------------- pair expansion (4-image chunk): h1 = relu(U[b]+V[a]+g1_b) bf16 ----------
__global__ __launch_bounds__(256)
void pair_kernel(const float* __restrict__ UV, const float* __restrict__ g1b,
                 u16* __restrict__ h1, int imgbase)
{
    const int pidx = blockIdx.y;
    const int img = imgbase + (pidx >> 12);
    const int a = (pidx >> 6) & 63, b = pidx & 63;
    const int col = blockIdx.x * 256 + threadIdx.x;
    const float v = UV[(size_t)(img * 64 + b) * 2560 + col]
                  + UV[(size_t)(img * 64 + a) * 2560 + 1280 + col] + g1b[col];
    h1[(size_t)pidx * 1280 + col] = f2bf(fmaxf(v, 0.f));
}

__global__ void zero_f32(float* __restrict__ p, int n) {
    const int i = blockIdx.x * 256 + threadIdx.x;
    if (i < n) p[i] = 0.f;
}

// =======================================================================================
extern "C" void kernel_launch(void* const* d_in, const int* in_sizes, int n_in,
                              void* d_out, int out_size, void* d_ws, size_t ws_size,
                              hipStream_t stream)
{
    const float* im_feat = (const float*)d_in[0];
    const float* boxes   = (const float*)d_in[1];
    const float* nboxes  = (const float*)d_in[2];
    const float* proj_w  = (const float*)d_in[3];
    const float* proj_b  = (const float*)d_in[4];
    const float* conv_w  = (const float*)d_in[5];
    const float* conv_b  = (const float*)d_in[6];
    const float* bn_g    = (const float*)d_in[7];
    const float* bn_b    = (const float*)d_in[8];
    const float* bn_m    = (const float*)d_in[9];
    const float* bn_v    = (const float*)d_in[10];
    const float* fc_w    = (const float*)d_in[11];
    const float* fc_b    = (const float*)d_in[12];
    const float* ln1_g   = (const float*)d_in[13];
    const float* ln1_b   = (const float*)d_in[14];
    const float* box_w   = (const float*)d_in[15];
    const float* box_b   = (const float*)d_in[16];
    const float* ln2_g   = (const float*)d_in[17];
    const float* ln2_b   = (const float*)d_in[18];
    const float* g1_w    = (const float*)d_in[19];
    const float* g1_b    = (const float*)d_in[20];
    const float* g2_w    = (const float*)d_in[21];
    const float* g2_b    = (const float*)d_in[22];
    const float* g3_w    = (const float*)d_in[23];
    const float* g3_b    = (const float*)d_in[24];
    float* out = (float*)d_out;
    (void)in_sizes; (void)n_in; (void)out_size; (void)ws_size;

    char* base = (char*)d_ws;
    size_t o = 0;
    auto carve = [&](size_t bytes) { char* p = base + o; o += (bytes + 15) & ~(size_t)15; return p; };
    float* x_cl    = (float*)carve(8388608);
    u16*   imT     = (u16*)  carve(8388608);
    u16*   convout = (u16*)  carve(12845056);
    float* fc_out  = (float*)carve(2097152);
    u16*   feats   = (u16*)  carve(1310720);
    float* UV      = (float*)carve(5242880);
    u16*   wpack   = (u16*)  carve(4718592);
    float* scale   = (float*)carve(1024);
    float* shift   = (float*)carve(1024);
    u16*   projwb  = (u16*)  carve(4194304);
    u16*   fcwb    = (u16*)  carve(25690112);
    u16*   g1wb    = (u16*)  carve(6553600);
    u16*   g2wb    = (u16*)  carve(3276800);
    u16*   g3wb    = (u16*)  carve(3276800);
    char*  big     = carve(84934656);
    u16*   r_pad   = (u16*)big;
    u16*   h1      = (u16*)big;
    u16*   h2      = (u16*)(big + 41943040);

    zero_f32<<<40, 256, 0, stream>>>(out, 10240);
    zero_f32<<<2048, 256, 0, stream>>>(fc_out, 524288);
    zero_f32<<<5120, 256, 0, stream>>>(UV, 1310720);

    cvt_bf16<<<2048, 256, 0, stream>>>(proj_w, projwb, 524288);
    cvt_bf16<<<12544, 256, 0, stream>>>(fc_w, fcwb, 3211264);
    cvt_bf16<<<1600, 256, 0, stream>>>(g2_w, g2wb, 409600);
    cvt_bf16<<<1600, 256, 0, stream>>>(g3_w, g3wb, 409600);
    pack_g1<<<3200, 256, 0, stream>>>(g1_w, g1wb);
    pack_conv<<<9216, 256, 0, stream>>>(conv_w, conv_b, bn_g, bn_b, bn_m, bn_v, wpack, scale, shift);

    transpose_proj<<<dim3(4, 32, 8), 256, 0, stream>>>(im_feat, imT);
    gemm_bf16<0, 1, 0><<<dim3(8, 16, 1), 256, 0, stream>>>(
        imT, projwb, proj_b, nullptr, x_cl, 2048, 1024, 2048, 2048, 2048, 1024);

    zero_halo<<<16384, 256, 0, stream>>>(r_pad);
    roialign_kernel<<<25088, 256, 0, stream>>>(x_cl, boxes, r_pad);

    gemm_bf16<2, 3, 1><<<dim3(2, 196, 1), 256, 0, stream>>>(
        r_pad, wpack, scale, shift, convout, 25088, 256, 9216, 0, 9216, 0);

    gemm_bf16<0, 0, 3><<<dim3(8, 4, 4), 256, 0, stream>>>(
        convout, fcwb, nullptr, nullptr, fc_out, 512, 1024, 3136, 12544, 12544, 1024);

    ln1_kernel<<<512, 256, 0, stream>>>(fc_out, fc_b, ln1_g, ln1_b, feats);
    box_kernel<<<512, 256, 0, stream>>>(nboxes, box_w, box_b, ln2_g, ln2_b, feats);

    gemm_bf16<0, 0, 3><<<dim3(20, 4, 2), 256, 0, stream>>>(
        feats, g1wb, nullptr, nullptr, UV, 512, 2560, 640, 1280, 1280, 2560);

    // -------- relation: 2 chunks of 4 images; g2/g3 on the new 256^2 kernel --------
    for (int h = 0; h < 2; ++h) {
        pair_kernel<<<dim3(5, 16384), 256, 0, stream>>>(UV, g1_b, h1, h * 4);
        gemm256<2, 4><<<dim3(5, 64), 512, 0, stream>>>(
            h1, g2wb, g2_b, h2, 1280, 1280, 1280, 1280);
        gemm256<2, 2><<<dim3(5, 64), 512, 0, stream>>>(
            h2, g3wb, g3_b, out + h * 4 * 1280, 1280, 1280, 1280, 1280);
    }
}